// Round 1
// baseline (1232.502 us; speedup 1.0000x reference)
//
#include <hip/hip_runtime.h>
#include <math.h>

#define NN 512
#define HH 256
#define BB 32
#define NE 130816

// ---------- reduction helpers ----------
__device__ inline float wave_reduce_sum(float v) {
#pragma unroll
    for (int o = 32; o > 0; o >>= 1) v += __shfl_xor(v, o, 64);
    return v;
}

// 256-thread block reduce; red[] must be __shared__ float[4]
__device__ inline float block_reduce_sum256(float v, float* red) {
    v = wave_reduce_sum(v);
    int w = threadIdx.x >> 6;
    if ((threadIdx.x & 63) == 0) red[w] = v;
    __syncthreads();
    v = red[0] + red[1] + red[2] + red[3];
    __syncthreads();
    return v;
}

// ---------- 1) schedule init + out zero ----------
__global__ void init_kernel(float* __restrict__ sched, float* __restrict__ out) {
    __shared__ float alpha_s[100];
    int tid = threadIdx.x;
    if (tid < 100) {
        const double PI_H = 3.14159265358979323846 * 0.5;
        double f1 = (((double)tid / 100.0) + 0.008) / 1.008 * PI_H;
        double f2 = (((double)(tid + 1) / 100.0) + 0.008) / 1.008 * PI_H;
        double c1 = cos(f1), c2 = cos(f2);
        double beta = 1.0 - (c2 * c2) / (c1 * c1);
        if (beta > 0.999) beta = 0.999;
        alpha_s[tid] = 1.0f - (float)beta;   // betas->f32, alphas = 1-betas (f32)
    }
    __syncthreads();
    if (tid == 0) {
        out[0] = 0.0f;                        // d_out is poisoned each call
        float cum = 1.0f;
        for (int k = 0; k < 100; k++) {
            cum *= alpha_s[k];                // cumprod in f32 like numpy
            sched[k]       = sqrtf(cum);
            sched[100 + k] = sqrtf(1.0f - cum);
        }
    }
}

// ---------- 2) t_emb and per-layer t_bias ----------
__global__ __launch_bounds__(256) void temb_kernel(
    const float* __restrict__ te_W1, const float* __restrict__ te_b1,
    const float* __restrict__ te_W2, const float* __restrict__ te_b2,
    const float* __restrict__ tp_W,  const float* __restrict__ tp_b,
    const int* __restrict__ t, float* __restrict__ tbias_out) {
    int b = blockIdx.x, tid = threadIdx.x;
    __shared__ float hid[HH], emb[HH];
    float tf = (float)t[b] / 100.0f;
    float z = tf * te_W1[tid] + te_b1[tid];
    hid[tid] = z / (1.0f + expf(-z));        // silu
    __syncthreads();
    float acc = te_b2[tid];
    for (int k = 0; k < HH; k++) acc = fmaf(hid[k], te_W2[k * HH + tid], acc);
    emb[tid] = acc;
    __syncthreads();
    for (int l = 0; l < 4; l++) {
        const float* W = tp_W + l * HH * HH;
        float a2 = tp_b[l * HH + tid];
        for (int k = 0; k < HH; k++) a2 = fmaf(emb[k], W[k * HH + tid], a2);
        tbias_out[l * (BB * HH) + b * HH + tid] = a2;
    }
}

// ---------- 3) adj_t + inverse row abs-sum ----------
__global__ __launch_bounds__(256) void adj_kernel(
    const float* __restrict__ adj0, const float* __restrict__ noise,
    const int* __restrict__ t, const float* __restrict__ sched,
    float* __restrict__ adjt, float* __restrict__ invrs) {
    __shared__ float red[4];
    const int bid = blockIdx.x;          // b*512 + i
    const int b = bid >> 9;
    const int ts = t[b];
    const float sab = sched[ts], som = sched[100 + ts];
    const size_t base = (size_t)bid * NN;
    const int tid = threadIdx.x;
    float s = 0.0f;
#pragma unroll
    for (int jj = 0; jj < 2; jj++) {
        int j = tid + jj * 256;
        float a = sab * adj0[base + j] + som * noise[base + j];
        adjt[base + j] = a;
        s += fabsf(a);
    }
    s = block_reduce_sum256(s, red);
    if (tid == 0) invrs[bid] = 1.0f / (s + 1.0f);
}

// ---------- 4) unified fp32 GEMM: C(Mx256) = A(MxK) @ B(Kx256) [+epilogue] ----------
// mode 0: +bias                         (h = adj_t @ ip_W + ip_b)
// mode 1: +bias                         (hm = h @ msg_W + msg_b)
// mode 2: *scale[row], per-rowblock B   (msg = rowscale * adj_t @ hm[b])
// mode 3: A switches h->msg at k=256; +bias +tbias[b] +resid (pre-LN h_new + h)
__global__ __launch_bounds__(256) void gemm_kernel(
    int mode, int K,
    const float* __restrict__ A, int lda,
    const float* __restrict__ A2,
    const float* __restrict__ B, int ldb, int bstride,
    const float* __restrict__ bias,
    const float* __restrict__ scale,
    const float* __restrict__ tbias,
    const float* __restrict__ resid,
    float* __restrict__ C) {
    __shared__ float As[16][132];   // [k][m], padded
    __shared__ float Bs[16][64];    // [k][n]
    const int row0 = blockIdx.x * 128;
    const int n0 = blockIdx.y * 64;
    const int tid = threadIdx.x;
    const int ty = tid >> 4, tx = tid & 15;      // 16x16 thread grid, 8x4 per thread
    const float* Bp = B + (size_t)(row0 >> 9) * (size_t)bstride;

    float acc[8][4];
#pragma unroll
    for (int i = 0; i < 8; i++)
#pragma unroll
        for (int j = 0; j < 4; j++) acc[i][j] = 0.0f;

    const int m_st = tid >> 1;           // staging: row within tile
    const int k8 = (tid & 1) * 8;        // staging: k-offset (8 floats)
    const int kb = tid >> 4;             // B staging row
    const int nb = (tid & 15) << 2;      // B staging col

    for (int k0 = 0; k0 < K; k0 += 16) {
        const float* Ause = A;
        int kk = k0;
        if (mode == 3 && k0 >= 256) { Ause = A2; kk = k0 - 256; }
        const float* ap = Ause + (size_t)(row0 + m_st) * lda + kk + k8;
        float4 v0 = *(const float4*)ap;
        float4 v1 = *(const float4*)(ap + 4);
        float4 bv = *(const float4*)(Bp + (size_t)(k0 + kb) * ldb + n0 + nb);
        As[k8 + 0][m_st] = v0.x; As[k8 + 1][m_st] = v0.y;
        As[k8 + 2][m_st] = v0.z; As[k8 + 3][m_st] = v0.w;
        As[k8 + 4][m_st] = v1.x; As[k8 + 5][m_st] = v1.y;
        As[k8 + 6][m_st] = v1.z; As[k8 + 7][m_st] = v1.w;
        *(float4*)&Bs[kb][nb] = bv;
        __syncthreads();
#pragma unroll
        for (int k = 0; k < 16; k++) {
            float a[8], bb[4];
            *(float4*)&a[0] = *(const float4*)&As[k][ty * 8];
            *(float4*)&a[4] = *(const float4*)&As[k][ty * 8 + 4];
            *(float4*)&bb[0] = *(const float4*)&Bs[k][tx * 4];
#pragma unroll
            for (int i = 0; i < 8; i++)
#pragma unroll
                for (int j = 0; j < 4; j++)
                    acc[i][j] = fmaf(a[i], bb[j], acc[i][j]);
        }
        __syncthreads();
    }

#pragma unroll
    for (int i = 0; i < 8; i++) {
        const int r = row0 + ty * 8 + i;
        float rs = 1.0f;
        if (mode == 2) rs = scale[r];
        float4 o;
        float* op = &o.x;
#pragma unroll
        for (int j = 0; j < 4; j++) {
            const int c = n0 + tx * 4 + j;
            float v = acc[i][j] * rs;
            if (bias) v += bias[c];
            if (mode == 3) v += tbias[((r >> 9) << 8) + c] + resid[(size_t)r * HH + c];
            op[j] = v;
        }
        *(float4*)(C + (size_t)r * HH + n0 + tx * 4) = o;
    }
}

// ---------- 5) layernorm: h = LN(pre) * g + b ----------
__global__ __launch_bounds__(256) void ln_kernel(
    const float* __restrict__ pre, const float* __restrict__ g,
    const float* __restrict__ b, float* __restrict__ h) {
    __shared__ float red[4];
    const size_t base = (size_t)blockIdx.x * HH;
    const int tid = threadIdx.x;
    float x = pre[base + tid];
    float mu = block_reduce_sum256(x, red) * (1.0f / HH);
    float d = x - mu;
    float var = block_reduce_sum256(d * d, red) * (1.0f / HH);
    h[base + tid] = d * rsqrtf(var + 1e-5f) * g[tid] + b[tid];
}

// ---------- 6) h_graph reduce + first output proj + silu ----------
__global__ __launch_bounds__(256) void final_kernel(
    const float* __restrict__ h, const float* __restrict__ op_W1,
    const float* __restrict__ op_b1, float* __restrict__ s_out) {
    int b = blockIdx.x, tid = threadIdx.x;
    __shared__ float hg[HH];
    const float* hp = h + (size_t)b * NN * HH;
    float acc = 0.0f;
    for (int i = 0; i < NN; i++) acc += hp[i * HH + tid];
    hg[tid] = acc;
    __syncthreads();
    float o = op_b1[tid];
    for (int k = 0; k < HH; k++) o = fmaf(hg[k], op_W1[k * HH + tid], o);
    s_out[b * HH + tid] = o / (1.0f + expf(-o));
}

// ---------- 7) fused second proj + triu target + MSE ----------
__global__ __launch_bounds__(256) void loss_kernel(
    const float* __restrict__ s, const float* __restrict__ op_W2,
    const float* __restrict__ op_b2, const float* __restrict__ noise,
    float* __restrict__ out) {
    __shared__ float sl[BB * HH];
    __shared__ float red[4];
    const int tid = threadIdx.x;
    for (int idx = tid; idx < BB * HH; idx += 256) sl[idx] = s[idx];
    __syncthreads();
    const int e0 = blockIdx.x * 512 + tid * 2;   // 2 pairs per thread
    float lsum = 0.0f;
    if (e0 < NE) {
        float2 acc[32];
#pragma unroll
        for (int b = 0; b < 32; b++) acc[b] = make_float2(0.0f, 0.0f);
        const float* w2 = op_W2 + e0;
        for (int h = 0; h < 256; h += 4) {
            float2 w0 = *(const float2*)(w2 + (size_t)(h + 0) * NE);
            float2 w1 = *(const float2*)(w2 + (size_t)(h + 1) * NE);
            float2 wv2 = *(const float2*)(w2 + (size_t)(h + 2) * NE);
            float2 w3 = *(const float2*)(w2 + (size_t)(h + 3) * NE);
#pragma unroll
            for (int b = 0; b < 32; b++) {
                float4 sv = *(const float4*)&sl[(b << 8) + h];  // wave-uniform broadcast
                acc[b].x = fmaf(sv.x, w0.x, acc[b].x); acc[b].y = fmaf(sv.x, w0.y, acc[b].y);
                acc[b].x = fmaf(sv.y, w1.x, acc[b].x); acc[b].y = fmaf(sv.y, w1.y, acc[b].y);
                acc[b].x = fmaf(sv.z, wv2.x, acc[b].x); acc[b].y = fmaf(sv.z, wv2.y, acc[b].y);
                acc[b].x = fmaf(sv.w, w3.x, acc[b].x); acc[b].y = fmaf(sv.w, w3.y, acc[b].y);
            }
        }
#pragma unroll
        for (int q = 0; q < 2; q++) {
            int e = e0 + q;
            float pb = op_b2[e];
            // e -> (i,j) upper-triangular, S(i) = i*(1023-i)/2
            int i = (int)((1023.0 - sqrt(1046529.0 - 8.0 * (double)e)) * 0.5);
            if (i < 0) i = 0;
            if (i > 510) i = 510;
            while (i > 0 && (i * (1023 - i)) / 2 > e) --i;
            while (((i + 1) * (1022 - i)) / 2 <= e) ++i;
            int j = i + 1 + (e - (i * (1023 - i)) / 2);
            const float* np = noise + (size_t)i * NN + j;
#pragma unroll
            for (int b = 0; b < 32; b++) {
                float p = (q == 0 ? acc[b].x : acc[b].y) + pb;
                float d = p - np[(size_t)b * NN * NN];
                lsum += d * d;
            }
        }
    }
    lsum *= (1.0f / (32.0f * (float)NE));
    lsum = block_reduce_sum256(lsum, red);
    if (tid == 0) atomicAdd(out, lsum);
}

// ---------- launch ----------
extern "C" void kernel_launch(void* const* d_in, const int* in_sizes, int n_in,
                              void* d_out, int out_size, void* d_ws, size_t ws_size,
                              hipStream_t stream) {
    const float* adj0  = (const float*)d_in[0];
    const float* noise = (const float*)d_in[1];
    const float* te_W1 = (const float*)d_in[2];
    const float* te_b1 = (const float*)d_in[3];
    const float* te_W2 = (const float*)d_in[4];
    const float* te_b2 = (const float*)d_in[5];
    const float* ip_W  = (const float*)d_in[6];
    const float* ip_b  = (const float*)d_in[7];
    const float* msg_W = (const float*)d_in[8];
    const float* msg_b = (const float*)d_in[9];
    const float* upd_W = (const float*)d_in[10];
    const float* upd_b = (const float*)d_in[11];
    const float* ln_g  = (const float*)d_in[12];
    const float* ln_b  = (const float*)d_in[13];
    const float* tp_W  = (const float*)d_in[14];
    const float* tp_b  = (const float*)d_in[15];
    const float* op_W1 = (const float*)d_in[16];
    const float* op_b1 = (const float*)d_in[17];
    const float* op_W2 = (const float*)d_in[18];
    const float* op_b2 = (const float*)d_in[19];
    const int*   t     = (const int*)d_in[20];
    float* out = (float*)d_out;

    float* ws = (float*)d_ws;
    float* sched = ws;                    // 256
    float* tbias = ws + 256;              // 4*32*256 = 32768
    float* invrs = ws + 33024;            // 16384
    float* sbuf  = ws + 49408;            // 8192
    float* adjt  = ws + 57600;            // 32*512*512 = 8388608
    float* h     = adjt + 8388608;        // 32*512*256 = 4194304
    float* hm    = h + 4194304;           // 4194304 (reused as pre-LN buffer)
    float* msg   = hm + 4194304;          // 4194304
    // total: ~84.1 MB of ws

    init_kernel<<<1, 128, 0, stream>>>(sched, out);
    temb_kernel<<<32, 256, 0, stream>>>(te_W1, te_b1, te_W2, te_b2, tp_W, tp_b, t, tbias);
    adj_kernel<<<BB * NN, 256, 0, stream>>>(adj0, noise, t, sched, adjt, invrs);

    dim3 ggrid(128, 4);   // M=16384 / 128, N=256 / 64
    // h = adj_t @ ip_W + ip_b
    gemm_kernel<<<ggrid, 256, 0, stream>>>(0, 512, adjt, 512, nullptr,
                                           ip_W, 256, 0, ip_b, nullptr, nullptr, nullptr, h);
    for (int l = 0; l < 4; l++) {
        // hm = h @ msg_W[l] + msg_b[l]
        gemm_kernel<<<ggrid, 256, 0, stream>>>(1, 256, h, 256, nullptr,
                                               msg_W + l * HH * HH, 256, 0,
                                               msg_b + l * HH, nullptr, nullptr, nullptr, hm);
        // msg = rowscale(adj_t @ hm[b])
        gemm_kernel<<<ggrid, 256, 0, stream>>>(2, 512, adjt, 512, nullptr,
                                               hm, 256, NN * HH,
                                               nullptr, invrs, nullptr, nullptr, msg);
        // pre = h@updW[:256] + msg@updW[256:] + upd_b + t_bias + h   (into hm buffer)
        gemm_kernel<<<ggrid, 256, 0, stream>>>(3, 512, h, 256, msg,
                                               upd_W + l * 2 * HH * HH, 256, 0,
                                               upd_b + l * HH, nullptr,
                                               tbias + l * BB * HH, h, hm);
        // h = LN(pre)*g + b
        ln_kernel<<<BB * NN, 256, 0, stream>>>(hm, ln_g + l * HH, ln_b + l * HH, h);
    }
    final_kernel<<<32, 256, 0, stream>>>(h, op_W1, op_b1, sbuf);
    loss_kernel<<<256, 256, 0, stream>>>(sbuf, op_W2, op_b2, noise, out);
}

// Round 2
// 766.145 us; speedup vs baseline: 1.6087x; 1.6087x over previous
//
#include <hip/hip_runtime.h>
#include <math.h>

#define NN 512
#define HH 256
#define BB 32
#define NE 130816

typedef unsigned short ushort_t;
using short8  = __attribute__((ext_vector_type(8))) short;
using floatx4 = __attribute__((ext_vector_type(4))) float;

// ---------- bf16 helpers (RNE) ----------
__device__ inline unsigned short f2bf(float f) {
    unsigned int u = __float_as_uint(f);
    unsigned int r = (u + 0x7fffu + ((u >> 16) & 1u)) >> 16;
    return (unsigned short)r;
}
__device__ inline float bf2f(unsigned short x) {
    return __uint_as_float(((unsigned int)x) << 16);
}

// ---------- reduction helpers ----------
__device__ inline float wave_reduce_sum(float v) {
#pragma unroll
    for (int o = 32; o > 0; o >>= 1) v += __shfl_xor(v, o, 64);
    return v;
}
__device__ inline float block_reduce_sum256(float v, float* red) {
    v = wave_reduce_sum(v);
    int w = threadIdx.x >> 6;
    if ((threadIdx.x & 63) == 0) red[w] = v;
    __syncthreads();
    v = red[0] + red[1] + red[2] + red[3];
    __syncthreads();
    return v;
}

// ---------- 1) schedule init + out zero ----------
__global__ void init_kernel(float* __restrict__ sched, float* __restrict__ out) {
    __shared__ float alpha_s[100];
    int tid = threadIdx.x;
    if (tid < 100) {
        const double PI_H = 3.14159265358979323846 * 0.5;
        double f1 = (((double)tid / 100.0) + 0.008) / 1.008 * PI_H;
        double f2 = (((double)(tid + 1) / 100.0) + 0.008) / 1.008 * PI_H;
        double c1 = cos(f1), c2 = cos(f2);
        double beta = 1.0 - (c2 * c2) / (c1 * c1);
        if (beta > 0.999) beta = 0.999;
        alpha_s[tid] = 1.0f - (float)beta;
    }
    __syncthreads();
    if (tid == 0) {
        out[0] = 0.0f;
        float cum = 1.0f;
        for (int k = 0; k < 100; k++) {
            cum *= alpha_s[k];
            sched[k]       = sqrtf(cum);
            sched[100 + k] = sqrtf(1.0f - cum);
        }
    }
}

// ---------- 2) t_emb and per-layer t_bias ----------
__global__ __launch_bounds__(256) void temb_kernel(
    const float* __restrict__ te_W1, const float* __restrict__ te_b1,
    const float* __restrict__ te_W2, const float* __restrict__ te_b2,
    const float* __restrict__ tp_W,  const float* __restrict__ tp_b,
    const int* __restrict__ t, float* __restrict__ tbias_out) {
    int b = blockIdx.x, tid = threadIdx.x;
    __shared__ float hid[HH], emb[HH];
    float tf = (float)t[b] / 100.0f;
    float z = tf * te_W1[tid] + te_b1[tid];
    hid[tid] = z / (1.0f + expf(-z));
    __syncthreads();
    float acc = te_b2[tid];
#pragma unroll 8
    for (int k = 0; k < HH; k++) acc = fmaf(hid[k], te_W2[k * HH + tid], acc);
    emb[tid] = acc;
    __syncthreads();
    for (int l = 0; l < 4; l++) {
        const float* W = tp_W + l * HH * HH;
        float a2 = tp_b[l * HH + tid];
#pragma unroll 8
        for (int k = 0; k < HH; k++) a2 = fmaf(emb[k], W[k * HH + tid], a2);
        tbias_out[l * (BB * HH) + b * HH + tid] = a2;
    }
}

// ---------- 3) adj_t (bf16) + inverse row abs-sum (fp32) ----------
__global__ __launch_bounds__(256) void adj_kernel(
    const float* __restrict__ adj0, const float* __restrict__ noise,
    const int* __restrict__ t, const float* __restrict__ sched,
    ushort_t* __restrict__ adjt_bf, float* __restrict__ invrs) {
    __shared__ float red[4];
    const int bid = blockIdx.x;          // b*512 + i
    const int b = bid >> 9;
    const int ts = t[b];
    const float sab = sched[ts], som = sched[100 + ts];
    const size_t base = (size_t)bid * NN;
    const int tid = threadIdx.x;
    float s = 0.0f;
#pragma unroll
    for (int jj = 0; jj < 2; jj++) {
        int j = tid + jj * 256;
        float a = sab * adj0[base + j] + som * noise[base + j];
        adjt_bf[base + j] = f2bf(a);
        s += fabsf(a);
    }
    s = block_reduce_sum256(s, red);
    if (tid == 0) invrs[bid] = 1.0f / (s + 1.0f);
}

// ---------- 4) weight transpose+convert: W (RxC f32) -> WT (CxR bf16) ----------
// z=0: ip_W (512x256); z=1..4: msg_W[l] (256x256); z=5..8: upd_W[l] (512x256)
__global__ __launch_bounds__(256) void wcvt_kernel(
    const float* __restrict__ ip_W, const float* __restrict__ msg_W,
    const float* __restrict__ upd_W,
    ushort_t* __restrict__ ipWT, ushort_t* __restrict__ msgWT,
    ushort_t* __restrict__ updWT) {
    const int z = blockIdx.z;
    const float* src; ushort_t* dst; int R;
    if (z == 0)      { src = ip_W;                          dst = ipWT;                       R = 512; }
    else if (z <= 4) { src = msg_W + (z - 1) * 65536;       dst = msgWT + (z - 1) * 65536;    R = 256; }
    else             { src = upd_W + (z - 5) * 131072;      dst = updWT + (z - 5) * 131072;   R = 512; }
    const int r0 = blockIdx.y * 32, c0 = blockIdx.x * 32;
    if (r0 >= R) return;
    __shared__ float T[32][33];
    const int tr = threadIdx.x >> 5, tc = threadIdx.x & 31;
#pragma unroll
    for (int s = 0; s < 32; s += 8)
        T[tr + s][tc] = src[(size_t)(r0 + tr + s) * 256 + c0 + tc];
    __syncthreads();
#pragma unroll
    for (int s = 0; s < 32; s += 8)
        dst[(size_t)(c0 + tr + s) * R + r0 + tc] = f2bf(T[tc][tr + s]);
}

// ---------- 5) bf16 transpose: hm (b,512,256) -> hmT (b,256,512) ----------
__global__ __launch_bounds__(256) void tpose_kernel(
    const ushort_t* __restrict__ src, ushort_t* __restrict__ dst) {
    const int b = blockIdx.z;
    const int j0 = blockIdx.y * 32, h0 = blockIdx.x * 32;
    const ushort_t* s = src + (size_t)b * NN * HH;
    ushort_t* d = dst + (size_t)b * NN * HH;
    __shared__ ushort_t T[32][34];
    const int tr = threadIdx.x >> 5, tc = threadIdx.x & 31;
#pragma unroll
    for (int ss = 0; ss < 32; ss += 8)
        T[tr + ss][tc] = s[(size_t)(j0 + tr + ss) * HH + h0 + tc];
    __syncthreads();
#pragma unroll
    for (int ss = 0; ss < 32; ss += 8)
        d[(size_t)(h0 + tr + ss) * NN + j0 + tc] = T[tc][tr + ss];
}

// ---------- 6) bf16 MFMA GEMM: C(Mx256) = A(MxK) @ B(Kx256) + epilogue ----------
// B supplied TRANSPOSED: BT[n][k] with leading dim ldbt; bstride per 512-row batch (mode 2).
// A2 non-null => A switches to A2 at k=256 (concat GEMM).
// epilogue: v = acc * (scale?scale[row]:1) + (bias?bias[col]:0)
//             + (tbias? tbias[(row>>9)*256+col] + bf16(resid[row*256+col]) : 0)
// stores: Cf (fp32) and/or Cb (bf16)
__global__ __launch_bounds__(256) void gemm_bf16(
    int K,
    const ushort_t* __restrict__ A, int lda, const ushort_t* __restrict__ A2,
    const ushort_t* __restrict__ BT, int ldbt, long long bstride,
    const float* __restrict__ bias, const float* __restrict__ scale,
    const float* __restrict__ tbias, const ushort_t* __restrict__ resid,
    float* __restrict__ Cf, ushort_t* __restrict__ Cb) {
    __shared__ ushort_t As[128][40];   // [m][k], pitch 40 (+8 pad)
    __shared__ ushort_t Bs[64][40];    // [n][k], pitch 40
    const int row0 = blockIdx.x * 128;
    const int n0 = blockIdx.y * 64;
    const int tid = threadIdx.x;
    const int lane = tid & 63;
    const int w = tid >> 6;
    const int l15 = lane & 15, quad = lane >> 4;
    const int wm = (w >> 1) * 64, wn = (w & 1) * 32;
    const ushort_t* Bp = BT + (size_t)(row0 >> 9) * (size_t)bstride;

    floatx4 acc[4][2];
#pragma unroll
    for (int i = 0; i < 4; i++)
#pragma unroll
        for (int j = 0; j < 2; j++) {
            acc[i][j][0] = 0.0f; acc[i][j][1] = 0.0f;
            acc[i][j][2] = 0.0f; acc[i][j][3] = 0.0f;
        }

    const int ma = tid >> 1, ka = (tid & 1) * 16;   // A staging
    const int nb = tid >> 2, kb = (tid & 3) * 8;    // B staging

    for (int kc = 0; kc < K; kc += 32) {
        const ushort_t* Ause = A; int kk = kc;
        if (A2 && kc >= 256) { Ause = A2; kk = kc - 256; }
        const ushort_t* ap = Ause + (size_t)(row0 + ma) * lda + kk + ka;
        uint4 av0 = *(const uint4*)ap;
        uint4 av1 = *(const uint4*)(ap + 8);
        uint4 bv = *(const uint4*)(Bp + (size_t)(n0 + nb) * ldbt + kc + kb);
        *(uint4*)&As[ma][ka]     = av0;
        *(uint4*)&As[ma][ka + 8] = av1;
        *(uint4*)&Bs[nb][kb]     = bv;
        __syncthreads();

        short8 af[4], bfr[2];
#pragma unroll
        for (int tm = 0; tm < 4; tm++)
            af[tm] = *(const short8*)&As[wm + tm * 16 + l15][quad * 8];
#pragma unroll
        for (int tn = 0; tn < 2; tn++)
            bfr[tn] = *(const short8*)&Bs[wn + tn * 16 + l15][quad * 8];
#pragma unroll
        for (int tm = 0; tm < 4; tm++)
#pragma unroll
            for (int tn = 0; tn < 2; tn++)
                acc[tm][tn] = __builtin_amdgcn_mfma_f32_16x16x32_bf16(
                    af[tm], bfr[tn], acc[tm][tn], 0, 0, 0);
        __syncthreads();
    }

#pragma unroll
    for (int tm = 0; tm < 4; tm++)
#pragma unroll
        for (int tn = 0; tn < 2; tn++) {
#pragma unroll
            for (int r = 0; r < 4; r++) {
                const int row = row0 + wm + tm * 16 + quad * 4 + r;
                const int col = n0 + wn + tn * 16 + l15;
                float v = acc[tm][tn][r];
                if (scale) v *= scale[row];
                if (bias) v += bias[col];
                if (tbias) v += tbias[((row >> 9) << 8) + col] + bf2f(resid[(size_t)row * HH + col]);
                if (Cf) Cf[(size_t)row * HH + col] = v;
                if (Cb) Cb[(size_t)row * HH + col] = f2bf(v);
            }
        }
}

// ---------- 7) layernorm: h_bf = bf16(LN(pre) * g + b) ----------
__global__ __launch_bounds__(256) void ln_kernel(
    const float* __restrict__ pre, const float* __restrict__ g,
    const float* __restrict__ b, ushort_t* __restrict__ h_bf) {
    __shared__ float red[4];
    const size_t base = (size_t)blockIdx.x * HH;
    const int tid = threadIdx.x;
    float x = pre[base + tid];
    float mu = block_reduce_sum256(x, red) * (1.0f / HH);
    float d = x - mu;
    float var = block_reduce_sum256(d * d, red) * (1.0f / HH);
    h_bf[base + tid] = f2bf(d * rsqrtf(var + 1e-5f) * g[tid] + b[tid]);
}

// ---------- 8) partial h_graph sums ----------
__global__ __launch_bounds__(256) void psum_kernel(
    const ushort_t* __restrict__ h_bf, float* __restrict__ partial) {
    const int b = blockIdx.x, ch = blockIdx.y, tid = threadIdx.x;
    const ushort_t* hp = h_bf + ((size_t)b * NN + ch * 32) * HH;
    float s = 0.0f;
#pragma unroll
    for (int i = 0; i < 32; i++) s += bf2f(hp[i * HH + tid]);
    partial[(((size_t)b * 16 + ch) << 8) + tid] = s;
}

// ---------- 9) h_graph reduce + first output proj + silu ----------
__global__ __launch_bounds__(256) void final_kernel(
    const float* __restrict__ partial, const float* __restrict__ op_W1,
    const float* __restrict__ op_b1, float* __restrict__ s_out) {
    int b = blockIdx.x, tid = threadIdx.x;
    __shared__ float hg[HH];
    float acc = 0.0f;
#pragma unroll
    for (int c = 0; c < 16; c++) acc += partial[(((size_t)b * 16 + c) << 8) + tid];
    hg[tid] = acc;
    __syncthreads();
    float o = op_b1[tid];
#pragma unroll 8
    for (int k = 0; k < HH; k++) o = fmaf(hg[k], op_W1[k * HH + tid], o);
    s_out[b * HH + tid] = o / (1.0f + expf(-o));
}

// ---------- 10) fused second proj + triu target + MSE ----------
__global__ __launch_bounds__(256) void loss_kernel(
    const float* __restrict__ s, const float* __restrict__ op_W2,
    const float* __restrict__ op_b2, const float* __restrict__ noise,
    float* __restrict__ out) {
    __shared__ float sl[BB * HH];
    __shared__ float red[4];
    const int tid = threadIdx.x;
    for (int idx = tid; idx < BB * HH; idx += 256) sl[idx] = s[idx];
    __syncthreads();
    const int e0 = blockIdx.x * 512 + tid * 2;
    float lsum = 0.0f;
    if (e0 < NE) {
        float2 acc[32];
#pragma unroll
        for (int b = 0; b < 32; b++) acc[b] = make_float2(0.0f, 0.0f);
        const float* w2 = op_W2 + e0;
        for (int h = 0; h < 256; h += 4) {
            float2 w0 = *(const float2*)(w2 + (size_t)(h + 0) * NE);
            float2 w1 = *(const float2*)(w2 + (size_t)(h + 1) * NE);
            float2 wv2 = *(const float2*)(w2 + (size_t)(h + 2) * NE);
            float2 w3 = *(const float2*)(w2 + (size_t)(h + 3) * NE);
#pragma unroll
            for (int b = 0; b < 32; b++) {
                float4 sv = *(const float4*)&sl[(b << 8) + h];
                acc[b].x = fmaf(sv.x, w0.x, acc[b].x); acc[b].y = fmaf(sv.x, w0.y, acc[b].y);
                acc[b].x = fmaf(sv.y, w1.x, acc[b].x); acc[b].y = fmaf(sv.y, w1.y, acc[b].y);
                acc[b].x = fmaf(sv.z, wv2.x, acc[b].x); acc[b].y = fmaf(sv.z, wv2.y, acc[b].y);
                acc[b].x = fmaf(sv.w, w3.x, acc[b].x); acc[b].y = fmaf(sv.w, w3.y, acc[b].y);
            }
        }
#pragma unroll
        for (int q = 0; q < 2; q++) {
            int e = e0 + q;
            float pb = op_b2[e];
            int i = (int)((1023.0 - sqrt(1046529.0 - 8.0 * (double)e)) * 0.5);
            if (i < 0) i = 0;
            if (i > 510) i = 510;
            while (i > 0 && (i * (1023 - i)) / 2 > e) --i;
            while (((i + 1) * (1022 - i)) / 2 <= e) ++i;
            int j = i + 1 + (e - (i * (1023 - i)) / 2);
            const float* np = noise + (size_t)i * NN + j;
#pragma unroll
            for (int b = 0; b < 32; b++) {
                float p = (q == 0 ? acc[b].x : acc[b].y) + pb;
                float d = p - np[(size_t)b * NN * NN];
                lsum += d * d;
            }
        }
    }
    lsum *= (1.0f / (32.0f * (float)NE));
    lsum = block_reduce_sum256(lsum, red);
    if (tid == 0) atomicAdd(out, lsum);
}

// ---------- launch ----------
extern "C" void kernel_launch(void* const* d_in, const int* in_sizes, int n_in,
                              void* d_out, int out_size, void* d_ws, size_t ws_size,
                              hipStream_t stream) {
    const float* adj0  = (const float*)d_in[0];
    const float* noise = (const float*)d_in[1];
    const float* te_W1 = (const float*)d_in[2];
    const float* te_b1 = (const float*)d_in[3];
    const float* te_W2 = (const float*)d_in[4];
    const float* te_b2 = (const float*)d_in[5];
    const float* ip_W  = (const float*)d_in[6];
    const float* ip_b  = (const float*)d_in[7];
    const float* msg_W = (const float*)d_in[8];
    const float* msg_b = (const float*)d_in[9];
    const float* upd_W = (const float*)d_in[10];
    const float* upd_b = (const float*)d_in[11];
    const float* ln_g  = (const float*)d_in[12];
    const float* ln_b  = (const float*)d_in[13];
    const float* tp_W  = (const float*)d_in[14];
    const float* tp_b  = (const float*)d_in[15];
    const float* op_W1 = (const float*)d_in[16];
    const float* op_b1 = (const float*)d_in[17];
    const float* op_W2 = (const float*)d_in[18];
    const float* op_b2 = (const float*)d_in[19];
    const int*   t     = (const int*)d_in[20];
    float* out = (float*)d_out;

    float* ws = (float*)d_ws;
    float* sched   = ws;                    // 256
    float* tbias   = ws + 256;              // 32768
    float* invrs   = ws + 33024;            // 16384
    float* sbuf    = ws + 49408;            // 8192
    float* partial = ws + 57600;            // 131072
    float* pre     = ws + 188672;           // 4194304
    ushort_t* bfb  = (ushort_t*)(ws + 4382976);
    ushort_t* adjt_bf = bfb;                // 8388608 ushorts
    ushort_t* h_bf    = bfb + 8388608;      // 4194304
    ushort_t* msg_bf  = bfb + 12582912;     // 4194304
    ushort_t* hm_bf   = bfb + 16777216;     // 4194304
    ushort_t* hmT_bf  = bfb + 20971520;     // 4194304
    ushort_t* ipWT    = bfb + 25165824;     // 131072
    ushort_t* msgWT   = bfb + 25296896;     // 262144
    ushort_t* updWT   = bfb + 25559040;     // 524288
    // total ~69.7 MB

    init_kernel<<<1, 128, 0, stream>>>(sched, out);
    wcvt_kernel<<<dim3(8, 16, 9), 256, 0, stream>>>(ip_W, msg_W, upd_W, ipWT, msgWT, updWT);
    temb_kernel<<<32, 256, 0, stream>>>(te_W1, te_b1, te_W2, te_b2, tp_W, tp_b, t, tbias);
    adj_kernel<<<BB * NN, 256, 0, stream>>>(adj0, noise, t, sched, adjt_bf, invrs);

    dim3 ggrid(128, 4);   // M=16384/128, N=256/64
    // h = bf16(adj_t @ ip_W + ip_b)
    gemm_bf16<<<ggrid, 256, 0, stream>>>(512, adjt_bf, 512, nullptr,
                                         ipWT, 512, 0,
                                         ip_b, nullptr, nullptr, nullptr,
                                         nullptr, h_bf);
    for (int l = 0; l < 4; l++) {
        // hm = bf16(h @ msg_W[l] + msg_b[l])
        gemm_bf16<<<ggrid, 256, 0, stream>>>(256, h_bf, 256, nullptr,
                                             msgWT + l * 65536, 256, 0,
                                             msg_b + l * HH, nullptr, nullptr, nullptr,
                                             nullptr, hm_bf);
        // hmT[b] = hm[b]^T
        tpose_kernel<<<dim3(8, 16, 32), 256, 0, stream>>>(hm_bf, hmT_bf);
        // msg = bf16(rowscale * (adj_t @ hm[b]))
        gemm_bf16<<<ggrid, 256, 0, stream>>>(512, adjt_bf, 512, nullptr,
                                             hmT_bf, 512, (long long)(HH * NN),
                                             nullptr, invrs, nullptr, nullptr,
                                             nullptr, msg_bf);
        // pre = h@updW[:256] + msg@updW[256:] + upd_b + t_bias + h
        gemm_bf16<<<ggrid, 256, 0, stream>>>(512, h_bf, 256, msg_bf,
                                             updWT + l * 131072, 512, 0,
                                             upd_b + l * HH, nullptr,
                                             tbias + l * BB * HH, h_bf,
                                             pre, nullptr);
        // h = bf16(LN(pre)*g + b)
        ln_kernel<<<BB * NN, 256, 0, stream>>>(pre, ln_g + l * HH, ln_b + l * HH, h_bf);
    }
    psum_kernel<<<dim3(32, 16), 256, 0, stream>>>(h_bf, partial);
    final_kernel<<<32, 256, 0, stream>>>(partial, op_W1, op_b1, sbuf);
    loss_kernel<<<256, 256, 0, stream>>>(sbuf, op_W2, op_b2, noise, out);
}